// Round 9
// baseline (699.257 us; speedup 1.0000x reference)
//
#include <hip/hip_runtime.h>
#include <math.h>

#define N_TOK 131072
#define K_CB  1024
#define D_DIM 64
#define MARGIN 0.0625f

// ws layout:
//   en[1024] f32        @ 0        (4 KB)
//   es frag-major bf16  @ 4096     (256 KB)   -> end 266240
//   fixcnt              @ 266240   (pad to 266256)
//   bklist[N] int       @ 266256   (512 KB)   -> end 790544
//   fixlist             @ 790544   (rest)
#define WS_EN     0
#define WS_ES     4096
#define WS_CNT    266240
#define WS_BK     266256
#define WS_LIST   790544

typedef short bf16x8 __attribute__((ext_vector_type(8)));
typedef float f32x4  __attribute__((ext_vector_type(4)));

__device__ __forceinline__ ushort f2bf(float f) {   // RNE fp32->bf16
    uint u = __float_as_uint(f);
    u += 0x7FFFu + ((u >> 16) & 1u);
    return (ushort)(u >> 16);
}
__device__ __forceinline__ float bf2f(ushort h) {
    return __uint_as_float(((uint)h) << 16);
}

// ---- kernel 1: prep. en[k] (R1-sequential rounding) + FRAG-MAJOR bf16 hi/lo split:
// es[(((cb*4+ks)*4+quad)*16+j)*8+e] (cb=k>>4, j=k&15): B-frag load for (cb,ks) is one
// contiguous 1KB wave load (lane = quad*16+j).
__global__ __launch_bounds__(256) void prep_kernel(
    const float* __restrict__ emb, float* __restrict__ en,
    ushort* __restrict__ es, uint* __restrict__ fixcnt)
{
    const int tid = threadIdx.x;
    const int pb  = blockIdx.x;
    const int c6  = tid & 63;
    const int q   = tid >> 6;
    const int code = pb * 64 + c6;
    if (pb == 0 && tid == 0) *fixcnt = 0;

    const int cb = code >> 4, jj = code & 15;
    const float* er = emb + (size_t)code * D_DIM;
    #pragma unroll
    for (int j = 0; j < 16; ++j) {
        int d = q * 16 + j;
        float f = er[d];
        ushort h = f2bf(f);
        ushort l = f2bf(f - bf2f(h));
        int ks = d >> 5, quad = (d >> 3) & 3, e = d & 7;
        es[(size_t)(((cb * 4 + ks)     * 4 + quad) * 16 + jj) * 8 + e] = h;
        es[(size_t)(((cb * 4 + ks + 2) * 4 + quad) * 16 + jj) * 8 + e] = l;
    }
    if (q == 0) {
        float s = 0.f;
        #pragma unroll
        for (int d = 0; d < D_DIM; ++d) s = fmaf(er[d], er[d], s);
        en[code] = s;
    }
}

// ---- kernel 2: compute only. Split-bf16 MFMA argmin (hi*hi + hi*lo + lo*hi),
// coalesced prefetched B-frags; emits bk[] (512 KB), zq (33 MB), fixlist.
// block = 256 thr = 4 waves x 32 rows = 128 rows/block; grid 1024.
__global__ __launch_bounds__(256) void vq_compute(
    const float* __restrict__ x, const float* __restrict__ emb,
    const float* __restrict__ en, const ushort* __restrict__ es,
    float* __restrict__ zq, int* __restrict__ bklist,
    uint* __restrict__ fixcnt, uint* __restrict__ fixlist, uint fixcap)
{
    const int tid  = threadIdx.x;
    const int wave = tid >> 6, lane = tid & 63;
    const int quad = lane >> 4, l15 = lane & 15;
    const int blockRow = blockIdx.x * 128;
    const int waveRow  = blockRow + wave * 32;

    __shared__ int lds_bk[128];   // wave-private 32-entry strips (no barrier needed)

    // A-frags per row-group g: [0]=hi d0..31, [1]=hi d32..63, [2]=lo d0..31, [3]=lo d32..63.
    // A layout (m120): A[m=lane&15][k=quad*8+j].
    bf16x8 af[2][4];
    #pragma unroll
    for (int g = 0; g < 2; ++g) {
        const float* xr = x + (size_t)(waveRow + g * 16 + l15) * D_DIM + quad * 8;
        f32x4 p0 = *(const f32x4*)(xr);
        f32x4 p1 = *(const f32x4*)(xr + 4);
        f32x4 p2 = *(const f32x4*)(xr + 32);
        f32x4 p3 = *(const f32x4*)(xr + 36);
        float v0[8], v1[8];
        #pragma unroll
        for (int j = 0; j < 4; ++j) { v0[j] = p0[j]; v0[4 + j] = p1[j]; v1[j] = p2[j]; v1[4 + j] = p3[j]; }
        #pragma unroll
        for (int j = 0; j < 8; ++j) {
            ushort h0 = f2bf(v0[j]);
            af[g][0][j] = (short)h0;
            af[g][2][j] = (short)f2bf(v0[j] - bf2f(h0));
            ushort h1 = f2bf(v1[j]);
            af[g][1][j] = (short)h1;
            af[g][3][j] = (short)f2bf(v1[j] - bf2f(h1));
        }
    }

    float b1[8], b2[8]; int k1[8];
    #pragma unroll
    for (int s = 0; s < 8; ++s) { b1[s] = INFINITY; b2[s] = INFINITY; k1[s] = 0; }

    const bf16x8* __restrict__ esv = (const bf16x8*)es;   // frag-major
    const int fidx = quad * 16 + l15;                     // == lane: contiguous 1KB per inst

    bf16x8 bc[4]; float enc;
    #pragma unroll
    for (int ks = 0; ks < 4; ++ks) bc[ks] = esv[ks * 64 + fidx];
    enc = en[l15];

    #pragma unroll 2
    for (int cb = 0; cb < 64; ++cb) {
        const int nb = (cb + 1) & 63;
        bf16x8 bn[4]; float enn;
        #pragma unroll
        for (int ks = 0; ks < 4; ++ks) bn[ks] = esv[(size_t)nb * 256 + ks * 64 + fidx];
        enn = en[nb * 16 + l15];

        f32x4 acc0 = {0.f, 0.f, 0.f, 0.f};
        f32x4 acc1 = {0.f, 0.f, 0.f, 0.f};
        // dot = xh*eh + xh*el + xl*eh  (xl*el ~1e-4, absorbed by MARGIN)
        acc0 = __builtin_amdgcn_mfma_f32_16x16x32_bf16(af[0][0], bc[0], acc0, 0, 0, 0);
        acc0 = __builtin_amdgcn_mfma_f32_16x16x32_bf16(af[0][1], bc[1], acc0, 0, 0, 0);
        acc0 = __builtin_amdgcn_mfma_f32_16x16x32_bf16(af[0][0], bc[2], acc0, 0, 0, 0);
        acc0 = __builtin_amdgcn_mfma_f32_16x16x32_bf16(af[0][1], bc[3], acc0, 0, 0, 0);
        acc0 = __builtin_amdgcn_mfma_f32_16x16x32_bf16(af[0][2], bc[0], acc0, 0, 0, 0);
        acc0 = __builtin_amdgcn_mfma_f32_16x16x32_bf16(af[0][3], bc[1], acc0, 0, 0, 0);
        acc1 = __builtin_amdgcn_mfma_f32_16x16x32_bf16(af[1][0], bc[0], acc1, 0, 0, 0);
        acc1 = __builtin_amdgcn_mfma_f32_16x16x32_bf16(af[1][1], bc[1], acc1, 0, 0, 0);
        acc1 = __builtin_amdgcn_mfma_f32_16x16x32_bf16(af[1][0], bc[2], acc1, 0, 0, 0);
        acc1 = __builtin_amdgcn_mfma_f32_16x16x32_bf16(af[1][1], bc[3], acc1, 0, 0, 0);
        acc1 = __builtin_amdgcn_mfma_f32_16x16x32_bf16(af[1][2], bc[0], acc1, 0, 0, 0);
        acc1 = __builtin_amdgcn_mfma_f32_16x16x32_bf16(af[1][3], bc[1], acc1, 0, 0, 0);

        const int code = cb * 16 + l15;
        // C layout (m89): col = lane&15 (this lane's code), row = quad*4 + r.
        #pragma unroll
        for (int r = 0; r < 4; ++r) {
            {
                float d = fmaf(-2.f, acc0[r], enc);
                bool lt = d < b1[r];
                b2[r] = lt ? b1[r] : fminf(b2[r], d);
                k1[r] = lt ? code : k1[r];
                b1[r] = lt ? d : b1[r];
            }
            {
                int s = 4 + r;
                float d = fmaf(-2.f, acc1[r], enc);
                bool lt = d < b1[s];
                b2[s] = lt ? b1[s] : fminf(b2[s], d);
                k1[s] = lt ? code : k1[s];
                b1[s] = lt ? d : b1[s];
            }
        }

        #pragma unroll
        for (int ks = 0; ks < 4; ++ks) bc[ks] = bn[ks];
        enc = enn;
    }

    // butterfly top-2 merge across the 16 lanes holding one row's columns
    #pragma unroll
    for (int s = 0; s < 8; ++s) {
        #pragma unroll
        for (int off = 1; off < 16; off <<= 1) {
            float ob1 = __shfl_xor(b1[s], off);
            int   ok1 = __shfl_xor(k1[s], off);
            float ob2 = __shfl_xor(b2[s], off);
            bool better = (ob1 < b1[s]) || (ob1 == b1[s] && ok1 < k1[s]);
            float loser = better ? b1[s] : ob1;
            b1[s] = better ? ob1 : b1[s];
            k1[s] = better ? ok1 : k1[s];
            b2[s] = fminf(fminf(b2[s], ob2), loser);
        }
    }

    // leaders publish bk: LDS strip (for zq) + global bklist (for writer) + fixlist
    if (l15 == 0) {
        #pragma unroll
        for (int s = 0; s < 8; ++s) {
            int lrow = wave * 32 + (s >> 2) * 16 + quad * 4 + (s & 3);
            lds_bk[lrow] = k1[s];
            bklist[blockRow + lrow] = k1[s];
            if (b2[s] - b1[s] <= MARGIN) {
                uint idx = atomicAdd(fixcnt, 1u);
                if (idx < fixcap)
                    fixlist[idx] = (uint)(blockRow + lrow) | ((uint)k1[s] << 17);
            }
        }
    }

    // zq: 8 groups of 4 rows; quad handles row mb*4+quad, l15 = col (16B each)
    #pragma unroll
    for (int mb = 0; mb < 8; ++mb) {
        int bk = lds_bk[wave * 32 + mb * 4 + quad];
        f32x4 v = ((const f32x4*)(emb + (size_t)bk * D_DIM))[l15];
        ((f32x4*)(zq + (size_t)(waveRow + mb * 4 + quad) * D_DIM))[l15] = v;
    }
}

// ---- kernel 3: one-hot writer — exact clone of the R6 fill kernel's addressing
// (plain dwordx4, grid-linear, 2048 blocks x 64 rows) + wave-uniform bk select.
// Proven store pattern: 536 MB at ~6.26 TB/s.
__global__ __launch_bounds__(256) void onehot_writer(
    const int* __restrict__ bklist, float* __restrict__ probs)
{
    const int tid = threadIdx.x;
    const int blk = blockIdx.x;
    const int c   = tid * 4;
    f32x4* p = (f32x4*)probs + (size_t)blk * 16384 + tid;   // 256 f32x4 per row
    const int* bkp = bklist + blk * 64;
    #pragma unroll
    for (int i = 0; i < 64; ++i) {
        const int bk = bkp[i];          // wave-uniform -> s_load broadcast
        f32x4 v;
        v[0] = (c     == bk) ? 1.f : 0.f;
        v[1] = (c + 1 == bk) ? 1.f : 0.f;
        v[2] = (c + 2 == bk) ? 1.f : 0.f;
        v[3] = (c + 3 == bk) ? 1.f : 0.f;
        p[(size_t)i * 256] = v;
    }
}

// ---- kernel 4: exact fp32 re-argmin (bit-identical to the R1/R2 formula) for flagged rows ----
__global__ __launch_bounds__(256) void vq_fixup(
    const float* __restrict__ x, const float* __restrict__ emb,
    const float* __restrict__ en,
    float* __restrict__ zq, float* __restrict__ probs,
    const uint* __restrict__ fixcnt, const uint* __restrict__ fixlist, uint fixcap)
{
    const int lane = threadIdx.x & 63;
    const uint gwave = (uint)((blockIdx.x * 256 + threadIdx.x) >> 6);
    uint cnt = *fixcnt;
    if (cnt > fixcap) cnt = fixcap;

    for (uint e = gwave; e < cnt; e += 1024u) {
        uint w = fixlist[e];
        int row = (int)(w & 0x1FFFFu);
        int kg  = (int)(w >> 17);
        const float* xr = x + (size_t)row * D_DIM;
        float xn = 0.f;
        #pragma unroll
        for (int d = 0; d < D_DIM; ++d) xn = fmaf(xr[d], xr[d], xn);

        float bd = INFINITY; int bk = 0;
        for (int t = 0; t < 16; ++t) {
            int code = t * 64 + lane;                 // ascending per lane
            const float* er = emb + (size_t)code * D_DIM;
            float a0 = 0.f, a1 = 0.f, a2 = 0.f, a3 = 0.f;
            #pragma unroll
            for (int d = 0; d < D_DIM; d += 4) {
                a0 = fmaf(xr[d + 0], er[d + 0], a0);
                a1 = fmaf(xr[d + 1], er[d + 1], a1);
                a2 = fmaf(xr[d + 2], er[d + 2], a2);
                a3 = fmaf(xr[d + 3], er[d + 3], a3);
            }
            float acc = (a0 + a1) + (a2 + a3);
            float dist = fmaf(-2.f, acc, xn + en[code]);
            if (dist < bd) { bd = dist; bk = code; }
        }
        #pragma unroll
        for (int off = 1; off < 64; off <<= 1) {
            float od = __shfl_xor(bd, off);
            int   ok = __shfl_xor(bk, off);
            if (od < bd || (od == bd && ok < bk)) { bd = od; bk = ok; }
        }
        if (bk != kg) {
            if (lane == 0) {
                probs[(size_t)row * K_CB + kg] = 0.f;
                probs[(size_t)row * K_CB + bk] = 1.f;
            }
            if (lane < 16)
                ((f32x4*)(zq + (size_t)row * D_DIM))[lane] =
                    ((const f32x4*)(emb + (size_t)bk * D_DIM))[lane];
        }
    }
}

extern "C" void kernel_launch(void* const* d_in, const int* in_sizes, int n_in,
                              void* d_out, int out_size, void* d_ws, size_t ws_size,
                              hipStream_t stream) {
    const float* x   = (const float*)d_in[0];   // [N, D] fp32
    const float* emb = (const float*)d_in[1];   // [K, D] fp32
    float* zq    = (float*)d_out;                              // [N, D]
    float* probs = (float*)d_out + (size_t)N_TOK * D_DIM;      // [N, K]

    char* ws = (char*)d_ws;
    float*  en      = (float*)(ws + WS_EN);
    ushort* es      = (ushort*)(ws + WS_ES);
    uint*   fixcnt  = (uint*)(ws + WS_CNT);
    int*    bklist  = (int*)(ws + WS_BK);
    uint*   fixlist = (uint*)(ws + WS_LIST);
    uint fixcap = (ws_size > WS_LIST + 4) ? (uint)((ws_size - WS_LIST) / 4) : 0u;

    prep_kernel<<<16, 256, 0, stream>>>(emb, en, es, fixcnt);
    vq_compute<<<N_TOK / 128, 256, 0, stream>>>(x, emb, en, es, zq, bklist, fixcnt, fixlist, fixcap);
    onehot_writer<<<N_TOK / 64, 256, 0, stream>>>(bklist, probs);
    vq_fixup<<<256, 256, 0, stream>>>(x, emb, en, zq, probs, fixcnt, fixlist, fixcap);
}

// Round 10
// 623.405 us; speedup vs baseline: 1.1217x; 1.1217x over previous
//
#include <hip/hip_runtime.h>
#include <math.h>

#define N_TOK 131072
#define K_CB  1024
#define D_DIM 64
#define MARGIN 0.03f

// ws layout: en[1024] f32 @0 ; es frag-major bf16 @4096 (256KB) ; fixcnt @266240 ; fixlist @266256
#define WS_EN     0
#define WS_ES     4096
#define WS_CNT    266240
#define WS_LIST   266256

typedef short bf16x8 __attribute__((ext_vector_type(8)));
typedef float f32x4  __attribute__((ext_vector_type(4)));

__device__ __forceinline__ ushort f2bf(float f) {   // RNE fp32->bf16
    uint u = __float_as_uint(f);
    u += 0x7FFFu + ((u >> 16) & 1u);
    return (ushort)(u >> 16);
}
__device__ __forceinline__ float bf2f(ushort h) {
    return __uint_as_float(((uint)h) << 16);
}

// ---- kernel 1: prep. en[k] + FRAG-MAJOR bf16 hi/lo split:
// es[(((cb*4+ks)*4+quad)*16+j)*8+e] (cb=k>>4, j=k&15): B-frag load for (cb,ks) is one
// contiguous 1KB wave load (lane = quad*16+j).
__global__ __launch_bounds__(256) void prep_kernel(
    const float* __restrict__ emb, float* __restrict__ en,
    ushort* __restrict__ es, uint* __restrict__ fixcnt)
{
    const int tid = threadIdx.x;
    const int pb  = blockIdx.x;
    const int c6  = tid & 63;
    const int q   = tid >> 6;
    const int code = pb * 64 + c6;
    if (pb == 0 && tid == 0) *fixcnt = 0;

    const int cb = code >> 4, jj = code & 15;
    const float* er = emb + (size_t)code * D_DIM;
    #pragma unroll
    for (int j = 0; j < 16; ++j) {
        int d = q * 16 + j;
        float f = er[d];
        ushort h = f2bf(f);
        ushort l = f2bf(f - bf2f(h));
        int ks = d >> 5, quad = (d >> 3) & 3, e = d & 7;
        es[(size_t)(((cb * 4 + ks)     * 4 + quad) * 16 + jj) * 8 + e] = h;
        es[(size_t)(((cb * 4 + ks + 2) * 4 + quad) * 16 + jj) * 8 + e] = l;
    }
    if (q == 0) {
        float s = 0.f;
        #pragma unroll
        for (int d = 0; d < D_DIM; ++d) s = fmaf(er[d], er[d], s);
        en[code] = s;
    }
}

// ---- kernel 2: fused, K-SPLIT waves. Block = 64 rows, 4 waves: wave (rg,h) handles
// rows rg*32..+32 x chunk-half h (512 codes). Top-2 merged across halves in LDS,
// then fused zq + one-hot blast (plain stores). Grid 2048 -> 32 waves/CU.
__global__ __launch_bounds__(256) void vq_onehot(
    const float* __restrict__ x, const float* __restrict__ emb,
    const float* __restrict__ en, const ushort* __restrict__ es,
    float* __restrict__ zq, float* __restrict__ probs,
    uint* __restrict__ fixcnt, uint* __restrict__ fixlist, uint fixcap)
{
    const int tid  = threadIdx.x;
    const int wave = tid >> 6, lane = tid & 63;
    const int quad = lane >> 4, l15 = lane & 15;
    const int rg = wave >> 1;          // row half (32 rows)
    const int h  = wave & 1;           // chunk half (32 chunks = 512 codes)
    const int blockRow = blockIdx.x * 64;
    const int waveRowBase = blockRow + rg * 32;

    __shared__ float lds_b1[2][64];
    __shared__ float lds_b2[2][64];
    __shared__ int   lds_k1[2][64];
    __shared__ int   lds_bk[64];

    // A-frags per row-group g: [0]=hi d0..31, [1]=hi d32..63, [2]=lo d0..31, [3]=lo d32..63.
    // A layout (m120): A[m=lane&15][k=quad*8+j].
    bf16x8 af[2][4];
    #pragma unroll
    for (int g = 0; g < 2; ++g) {
        const float* xr = x + (size_t)(waveRowBase + g * 16 + l15) * D_DIM + quad * 8;
        f32x4 p0 = *(const f32x4*)(xr);
        f32x4 p1 = *(const f32x4*)(xr + 4);
        f32x4 p2 = *(const f32x4*)(xr + 32);
        f32x4 p3 = *(const f32x4*)(xr + 36);
        float v0[8], v1[8];
        #pragma unroll
        for (int j = 0; j < 4; ++j) { v0[j] = p0[j]; v0[4 + j] = p1[j]; v1[j] = p2[j]; v1[4 + j] = p3[j]; }
        #pragma unroll
        for (int j = 0; j < 8; ++j) {
            ushort h0 = f2bf(v0[j]);
            af[g][0][j] = (short)h0;
            af[g][2][j] = (short)f2bf(v0[j] - bf2f(h0));
            ushort h1 = f2bf(v1[j]);
            af[g][1][j] = (short)h1;
            af[g][3][j] = (short)f2bf(v1[j] - bf2f(h1));
        }
    }

    float b1[8], b2[8]; int k1[8];
    #pragma unroll
    for (int s = 0; s < 8; ++s) { b1[s] = INFINITY; b2[s] = INFINITY; k1[s] = 0; }

    const bf16x8* __restrict__ esv = (const bf16x8*)es;   // frag-major
    const int fidx = quad * 16 + l15;                     // contiguous 1KB per inst
    const int cb0  = h * 32;

    bf16x8 bc[4]; float enc;
    #pragma unroll
    for (int ks = 0; ks < 4; ++ks) bc[ks] = esv[(size_t)cb0 * 256 + ks * 64 + fidx];
    enc = en[cb0 * 16 + l15];

    #pragma unroll 2
    for (int i = 0; i < 32; ++i) {
        const int cb  = cb0 + i;
        const int nbi = cb0 + ((i + 1) & 31);
        bf16x8 bn[4]; float enn;
        #pragma unroll
        for (int ks = 0; ks < 4; ++ks) bn[ks] = esv[(size_t)nbi * 256 + ks * 64 + fidx];
        enn = en[nbi * 16 + l15];

        f32x4 acc0 = {0.f, 0.f, 0.f, 0.f};
        f32x4 acc1 = {0.f, 0.f, 0.f, 0.f};
        // dot = xh*eh + xh*el + xl*eh  (xl*el ~1e-4, absorbed by MARGIN)
        acc0 = __builtin_amdgcn_mfma_f32_16x16x32_bf16(af[0][0], bc[0], acc0, 0, 0, 0);
        acc0 = __builtin_amdgcn_mfma_f32_16x16x32_bf16(af[0][1], bc[1], acc0, 0, 0, 0);
        acc0 = __builtin_amdgcn_mfma_f32_16x16x32_bf16(af[0][0], bc[2], acc0, 0, 0, 0);
        acc0 = __builtin_amdgcn_mfma_f32_16x16x32_bf16(af[0][1], bc[3], acc0, 0, 0, 0);
        acc0 = __builtin_amdgcn_mfma_f32_16x16x32_bf16(af[0][2], bc[0], acc0, 0, 0, 0);
        acc0 = __builtin_amdgcn_mfma_f32_16x16x32_bf16(af[0][3], bc[1], acc0, 0, 0, 0);
        acc1 = __builtin_amdgcn_mfma_f32_16x16x32_bf16(af[1][0], bc[0], acc1, 0, 0, 0);
        acc1 = __builtin_amdgcn_mfma_f32_16x16x32_bf16(af[1][1], bc[1], acc1, 0, 0, 0);
        acc1 = __builtin_amdgcn_mfma_f32_16x16x32_bf16(af[1][0], bc[2], acc1, 0, 0, 0);
        acc1 = __builtin_amdgcn_mfma_f32_16x16x32_bf16(af[1][1], bc[3], acc1, 0, 0, 0);
        acc1 = __builtin_amdgcn_mfma_f32_16x16x32_bf16(af[1][2], bc[0], acc1, 0, 0, 0);
        acc1 = __builtin_amdgcn_mfma_f32_16x16x32_bf16(af[1][3], bc[1], acc1, 0, 0, 0);

        const int code = cb * 16 + l15;
        // C layout (m89): col = lane&15 (this lane's code), row = quad*4 + r.
        #pragma unroll
        for (int r = 0; r < 4; ++r) {
            {
                float d = fmaf(-2.f, acc0[r], enc);
                bool lt = d < b1[r];
                b2[r] = lt ? b1[r] : fminf(b2[r], d);
                k1[r] = lt ? code : k1[r];
                b1[r] = lt ? d : b1[r];
            }
            {
                int s = 4 + r;
                float d = fmaf(-2.f, acc1[r], enc);
                bool lt = d < b1[s];
                b2[s] = lt ? b1[s] : fminf(b2[s], d);
                k1[s] = lt ? code : k1[s];
                b1[s] = lt ? d : b1[s];
            }
        }

        #pragma unroll
        for (int ks = 0; ks < 4; ++ks) bc[ks] = bn[ks];
        enc = enn;
    }

    // butterfly top-2 merge across the 16 lanes holding one row's columns
    #pragma unroll
    for (int s = 0; s < 8; ++s) {
        #pragma unroll
        for (int off = 1; off < 16; off <<= 1) {
            float ob1 = __shfl_xor(b1[s], off);
            int   ok1 = __shfl_xor(k1[s], off);
            float ob2 = __shfl_xor(b2[s], off);
            bool better = (ob1 < b1[s]) || (ob1 == b1[s] && ok1 < k1[s]);
            float loser = better ? b1[s] : ob1;
            b1[s] = better ? ob1 : b1[s];
            k1[s] = better ? ok1 : k1[s];
            b2[s] = fminf(fminf(b2[s], ob2), loser);
        }
    }

    // publish per-half stats
    if (l15 == 0) {
        #pragma unroll
        for (int s = 0; s < 8; ++s) {
            int idx = rg * 32 + (s >> 2) * 16 + quad * 4 + (s & 3);  // 0..63 in-block row
            lds_b1[h][idx] = b1[s];
            lds_b2[h][idx] = b2[s];
            lds_k1[h][idx] = k1[s];
        }
    }
    __syncthreads();

    // merge chunk halves (half-0 codes all smaller -> wins ties = first-min)
    if (tid < 64) {
        float a1 = lds_b1[0][tid], a2 = lds_b2[0][tid]; int ak = lds_k1[0][tid];
        float c1 = lds_b1[1][tid], c2 = lds_b2[1][tid]; int ck = lds_k1[1][tid];
        bool bwin = c1 < a1;
        float m1 = bwin ? c1 : a1;
        int   mk = bwin ? ck : ak;
        float loser = bwin ? a1 : c1;
        float m2 = fminf(fminf(a2, c2), loser);
        lds_bk[tid] = mk;
        if (m2 - m1 <= MARGIN) {
            uint idx = atomicAdd(fixcnt, 1u);
            if (idx < fixcap) fixlist[idx] = (uint)(blockRow + tid) | ((uint)mk << 17);
        }
    }
    __syncthreads();

    // zq: wave w writes rows [w*16, w*16+16): 4 rows/step, quad = row, l15 = col
    #pragma unroll
    for (int mb = 0; mb < 4; ++mb) {
        int rl = wave * 16 + mb * 4 + quad;
        int bk = lds_bk[rl];
        f32x4 v = ((const f32x4*)(emb + (size_t)bk * D_DIM))[l15];
        ((f32x4*)(zq + (size_t)(blockRow + rl) * D_DIM))[l15] = v;
    }

    // one-hot blast: wave w streams its 16 rows x 4KB, plain coalesced stores
    for (int m = 0; m < 16; ++m) {
        int rl = wave * 16 + m;
        int bk = lds_bk[rl];                     // uniform -> LDS broadcast
        float* prow = probs + (size_t)(blockRow + rl) * K_CB;
        #pragma unroll
        for (int s = 0; s < 4; ++s) {
            int c = s * 256 + lane * 4;
            f32x4 v;
            v[0] = (c     == bk) ? 1.f : 0.f;
            v[1] = (c + 1 == bk) ? 1.f : 0.f;
            v[2] = (c + 2 == bk) ? 1.f : 0.f;
            v[3] = (c + 3 == bk) ? 1.f : 0.f;
            *(f32x4*)(prow + c) = v;
        }
    }
}

// ---- kernel 3: exact fp32 re-argmin for flagged rows, coalesced: wave-per-row,
// lane = (code l15) x (d-slice quad); 16-line (not 64-line) loads + shfl reduce.
__global__ __launch_bounds__(256) void vq_fixup(
    const float* __restrict__ x, const float* __restrict__ emb,
    const float* __restrict__ en,
    float* __restrict__ zq, float* __restrict__ probs,
    const uint* __restrict__ fixcnt, const uint* __restrict__ fixlist, uint fixcap)
{
    const int lane = threadIdx.x & 63;
    const int quad = lane >> 4, l15 = lane & 15;
    const uint gwave = (uint)((blockIdx.x * 256 + threadIdx.x) >> 6);
    uint cnt = *fixcnt;
    if (cnt > fixcap) cnt = fixcap;

    for (uint e = gwave; e < cnt; e += 1024u) {
        uint w = fixlist[e];
        int row = (int)(w & 0x1FFFFu);
        int kg  = (int)(w >> 17);

        // x d-slice for this quad: d in [quad*16, quad*16+16)
        const f32x4* xr4 = (const f32x4*)(x + (size_t)row * D_DIM) + quad * 4;
        f32x4 xv[4];
        #pragma unroll
        for (int c = 0; c < 4; ++c) xv[c] = xr4[c];
        float xn = 0.f;
        #pragma unroll
        for (int c = 0; c < 4; ++c)
            #pragma unroll
            for (int j = 0; j < 4; ++j) xn = fmaf(xv[c][j], xv[c][j], xn);
        xn += __shfl_xor(xn, 16);
        xn += __shfl_xor(xn, 32);

        float bd = INFINITY; int bk = 0;
        for (int t = 0; t < 64; ++t) {
            int code = t * 16 + l15;                 // ascending per lane
            const f32x4* er4 = (const f32x4*)(emb + (size_t)code * D_DIM) + quad * 4;
            float dot = 0.f;
            #pragma unroll
            for (int c = 0; c < 4; ++c) {
                f32x4 ev = er4[c];
                #pragma unroll
                for (int j = 0; j < 4; ++j) dot = fmaf(xv[c][j], ev[j], dot);
            }
            dot += __shfl_xor(dot, 16);              // sum 4 quad partials
            dot += __shfl_xor(dot, 32);
            float dist = fmaf(-2.f, dot, xn + en[code]);
            if (dist < bd) { bd = dist; bk = code; } // strict <, ascending codes
        }
        #pragma unroll
        for (int off = 1; off < 16; off <<= 1) {     // codes live across l15 group
            float od = __shfl_xor(bd, off);
            int   ok = __shfl_xor(bk, off);
            if (od < bd || (od == bd && ok < bk)) { bd = od; bk = ok; }
        }
        if (bk != kg) {
            if (lane == 0) {
                probs[(size_t)row * K_CB + kg] = 0.f;
                probs[(size_t)row * K_CB + bk] = 1.f;
            }
            if (lane < 16)
                ((f32x4*)(zq + (size_t)row * D_DIM))[lane] =
                    ((const f32x4*)(emb + (size_t)bk * D_DIM))[lane];
        }
    }
}

extern "C" void kernel_launch(void* const* d_in, const int* in_sizes, int n_in,
                              void* d_out, int out_size, void* d_ws, size_t ws_size,
                              hipStream_t stream) {
    const float* x   = (const float*)d_in[0];   // [N, D] fp32
    const float* emb = (const float*)d_in[1];   // [K, D] fp32
    float* zq    = (float*)d_out;                              // [N, D]
    float* probs = (float*)d_out + (size_t)N_TOK * D_DIM;      // [N, K]

    char* ws = (char*)d_ws;
    float*  en      = (float*)(ws + WS_EN);
    ushort* es      = (ushort*)(ws + WS_ES);
    uint*   fixcnt  = (uint*)(ws + WS_CNT);
    uint*   fixlist = (uint*)(ws + WS_LIST);
    uint fixcap = (ws_size > WS_LIST + 4) ? (uint)((ws_size - WS_LIST) / 4) : 0u;

    prep_kernel<<<16, 256, 0, stream>>>(emb, en, es, fixcnt);
    vq_onehot<<<N_TOK / 64, 256, 0, stream>>>(x, emb, en, es, zq, probs, fixcnt, fixlist, fixcap);
    vq_fixup<<<256, 256, 0, stream>>>(x, emb, en, zq, probs, fixcnt, fixlist, fixcap);
}